// Round 3
// baseline (350.912 us; speedup 1.0000x reference)
//
#include <hip/hip_runtime.h>

#define FIN 128
#define HC 16
#define NCHUNK 8
#define BPC 64
#define RMAX 12512   // >= ceil(100000/8)=12500 ; 50,048 B LDS

// ---- phase 1: per-(chunk,block-slice) LDS histogram -> u16 partial counts ----
__global__ void hist_part_kernel(const int* __restrict__ dst, unsigned short* __restrict__ partial,
                                 int n, int E, int R) {
    __shared__ int lcnt[RMAX];
    int c = blockIdx.x & (NCHUNK - 1);
    int b = blockIdx.x >> 3;
    int lo = c * R, hi = min(n, lo + R), range = hi - lo;
    for (int i = threadIdx.x; i < range; i += 256) lcnt[i] = 0;
    __syncthreads();
    int Epb = (E + BPC - 1) / BPC;
    int s = b * Epb, e = min(E, s + Epb);
    for (int i = s + threadIdx.x; i < e; i += 256) {
        int d = dst[i];
        if (d >= lo && d < hi) atomicAdd(&lcnt[d - lo], 1);
    }
    __syncthreads();
    unsigned short* row = partial + (size_t)b * n + lo;
    for (int i = threadIdx.x; i < range; i += 256) row[i] = (unsigned short)lcnt[i];
}

// ---- phase 2: per-node scan over blocks (in-place -> exclusive bases), cnt, dis ----
__global__ void colscan_kernel(unsigned short* __restrict__ partial, int* __restrict__ cnt,
                               float* __restrict__ dis, int n) {
    int i = blockIdx.x * 256 + threadIdx.x;
    if (i >= n) return;
    int run = 0;
#pragma unroll 8
    for (int b = 0; b < BPC; ++b) {
        size_t idx = (size_t)b * n + i;
        int v = partial[idx];
        partial[idx] = (unsigned short)run;   // deg(node) << 65536, safe
        run += v;
    }
    cnt[i] = run;
    dis[i] = rsqrtf((float)run + 1.0f);       // +1 self-loop
}

// ---- 3-phase exclusive scan of cnt[n] -> offs[n] ----
__global__ void scan_bsum_kernel(const int* __restrict__ cnt, int* __restrict__ bsum, int n) {
    __shared__ int s[256];
    int t = threadIdx.x;
    int i = blockIdx.x * 256 + t;
    s[t] = (i < n) ? cnt[i] : 0;
    __syncthreads();
    for (int off = 128; off > 0; off >>= 1) {
        if (t < off) s[t] += s[t + off];
        __syncthreads();
    }
    if (t == 0) bsum[blockIdx.x] = s[0];
}

__global__ void scan_top_kernel(const int* __restrict__ bsum, int* __restrict__ bsumEx, int nb) {
    __shared__ int s[512];
    int t = threadIdx.x;
    s[t] = (t < nb) ? bsum[t] : 0;
    __syncthreads();
    for (int off = 1; off < 512; off <<= 1) {
        int v = (t >= off) ? s[t - off] : 0;
        __syncthreads();
        s[t] += v;
        __syncthreads();
    }
    if (t < nb) bsumEx[t] = s[t] - bsum[t];
}

__global__ void scan_final_kernel(const int* __restrict__ cnt, const int* __restrict__ bsumEx,
                                  int* __restrict__ offs, int n) {
    __shared__ int s[256];
    int t = threadIdx.x;
    int i = blockIdx.x * 256 + t;
    int v = (i < n) ? cnt[i] : 0;
    s[t] = v;
    __syncthreads();
    for (int off = 1; off < 256; off <<= 1) {
        int u = (t >= off) ? s[t - off] : 0;
        __syncthreads();
        s[t] += u;
        __syncthreads();
    }
    if (i < n) offs[i] = bsumEx[blockIdx.x] + s[t] - v;
}

// ---- phase 3: LDS cursors (offs + base) assign unique CSR slots, plain writes ----
__global__ void rank_scatter_kernel(const int* __restrict__ src, const int* __restrict__ dst,
                                    const unsigned short* __restrict__ partial,
                                    const int* __restrict__ offs, int* __restrict__ csr,
                                    int n, int E, int R) {
    __shared__ int cursor[RMAX];
    int c = blockIdx.x & (NCHUNK - 1);
    int b = blockIdx.x >> 3;
    int lo = c * R, hi = min(n, lo + R), range = hi - lo;
    const unsigned short* prow = partial + (size_t)b * n + lo;
    const int* orow = offs + lo;
    for (int i = threadIdx.x; i < range; i += 256) cursor[i] = orow[i] + (int)prow[i];
    __syncthreads();
    int Epb = (E + BPC - 1) / BPC;
    int s = b * Epb, e = min(E, s + Epb);
    for (int i = s + threadIdx.x; i < e; i += 256) {
        int d = dst[i];
        if (d >= lo && d < hi) {
            int slot = atomicAdd(&cursor[d - lo], 1);
            csr[slot] = src[i];
        }
    }
}

// hs[i][c] = (x[i] @ W1)[c] * dis[i]
__global__ void h1_matmul_kernel(const float* __restrict__ x, const float* __restrict__ W1,
                                 const float* __restrict__ dis, float* __restrict__ hs, int n) {
    __shared__ float W1s[FIN * HC];
    int tid = threadIdx.x;
    for (int i = tid; i < FIN * HC; i += 256) W1s[i] = W1[i];
    __syncthreads();
    int row = blockIdx.x * 16 + (tid >> 4);
    int col = tid & 15;
    if (row >= n) return;
    const float4* xr = (const float4*)(x + (size_t)row * FIN);
    float acc = 0.f;
#pragma unroll
    for (int k4 = 0; k4 < FIN / 4; ++k4) {
        float4 v = xr[k4];
        acc += v.x * W1s[(k4 * 4 + 0) * HC + col];
        acc += v.y * W1s[(k4 * 4 + 1) * HC + col];
        acc += v.z * W1s[(k4 * 4 + 2) * HC + col];
        acc += v.w * W1s[(k4 * 4 + 3) * HC + col];
    }
    hs[row * HC + col] = acc * dis[row];
}

// pull layer1: ONE WAVE per node (4 neighbors in flight x 16 channels)
__global__ void pull_layer1_kernel(const int* __restrict__ offs, const int* __restrict__ cnt,
                                   const int* __restrict__ csr, const float* __restrict__ hs,
                                   const float* __restrict__ dis, const float* __restrict__ b1,
                                   const float* __restrict__ W2, float* __restrict__ h2s, int n) {
    int node = (blockIdx.x * blockDim.x + threadIdx.x) >> 6;
    if (node >= n) return;
    int lane = threadIdx.x & 63;
    int c = lane & 15, q = lane >> 4;
    int start = offs[node];
    int m = cnt[node];
    float a = 0.f;
    for (int k = q; k < m; k += 4) a += hs[(size_t)csr[start + k] * HC + c];
    a += __shfl_xor(a, 16);
    a += __shfl_xor(a, 32);
    float d = dis[node];
    float h1 = fmaxf(d * (a + hs[(size_t)node * HC + c]) + b1[c], 0.f);
    float v = h1 * W2[c];
    v += __shfl_xor(v, 1);
    v += __shfl_xor(v, 2);
    v += __shfl_xor(v, 4);
    v += __shfl_xor(v, 8);
    if (lane == 0) h2s[node] = v * d;
}

// pull layer2 + epilogue: 8 lanes per node
__global__ void pull_layer2_kernel(const int* __restrict__ offs, const int* __restrict__ cnt,
                                   const int* __restrict__ csr, const float* __restrict__ h2s,
                                   const float* __restrict__ dis, const float* __restrict__ b2,
                                   float* __restrict__ out, int n) {
    int g = blockIdx.x * blockDim.x + threadIdx.x;
    int node = g >> 3;
    if (node >= n) return;
    int q = g & 7;
    int start = offs[node];
    int m = cnt[node];
    float a = 0.f;
    for (int k = q; k < m; k += 8) a += h2s[csr[start + k]];
    a += __shfl_xor(a, 1);
    a += __shfl_xor(a, 2);
    a += __shfl_xor(a, 4);
    if (q == 0) out[node] = dis[node] * (a + h2s[node]) + b2[0];
}

extern "C" void kernel_launch(void* const* d_in, const int* in_sizes, int n_in,
                              void* d_out, int out_size, void* d_ws, size_t ws_size,
                              hipStream_t stream) {
    const float* x  = (const float*)d_in[0];
    const int* ei   = (const int*)d_in[1];
    const float* W1 = (const float*)d_in[2];
    const float* b1 = (const float*)d_in[3];
    const float* W2 = (const float*)d_in[4];
    const float* b2 = (const float*)d_in[5];
    float* out = (float*)d_out;

    const int n = in_sizes[0] / FIN;   // 100000
    const int E = in_sizes[1] / 2;     // 3200000
    const int* src = ei;
    const int* dst = ei + E;
    const int R = (n + NCHUNK - 1) / NCHUNK;   // 12500

    // workspace layout (~34 MB)
    unsigned short* partial = (unsigned short*)d_ws;        // BPC*n u16 = 12.8MB
    int* csr    = (int*)(partial + (size_t)BPC * n);        // E
    int* offs   = csr + E;                                  // n
    int* cnt    = offs + n;                                 // n
    int* bsum   = cnt + n;                                  // 512
    int* bsumEx = bsum + 512;                               // 512
    float* dis  = (float*)(bsumEx + 512);                   // n
    float* hs   = dis + n;                                  // 16n
    float* h2s  = hs + (size_t)16 * n;                      // n

    const int nb = (n + 255) / 256;   // 391

    hist_part_kernel<<<NCHUNK * BPC, 256, 0, stream>>>(dst, partial, n, E, R);
    colscan_kernel<<<nb, 256, 0, stream>>>(partial, cnt, dis, n);
    scan_bsum_kernel<<<nb, 256, 0, stream>>>(cnt, bsum, n);
    scan_top_kernel<<<1, 512, 0, stream>>>(bsum, bsumEx, nb);
    scan_final_kernel<<<nb, 256, 0, stream>>>(cnt, bsumEx, offs, n);
    rank_scatter_kernel<<<NCHUNK * BPC, 256, 0, stream>>>(src, dst, partial, offs, csr, n, E, R);

    h1_matmul_kernel<<<(n + 15) / 16, 256, 0, stream>>>(x, W1, dis, hs, n);

    pull_layer1_kernel<<<(n * 64 + 255) / 256, 256, 0, stream>>>(offs, cnt, csr, hs, dis, b1, W2, h2s, n);
    pull_layer2_kernel<<<(n * 8 + 255) / 256, 256, 0, stream>>>(offs, cnt, csr, h2s, dis, b2, out, n);
}